// Round 9
// baseline (179.770 us; speedup 1.0000x reference)
//
#include <hip/hip_runtime.h>
#include <hip/hip_bf16.h>
#include <math.h>

// HIR rainfall-runoff scan — bracketed time-chunking, hi/lo split across waves.
//
// Step math: heaviside -> min/max (exact, continuous), redundant clamps
// removed (proven), exp(-SQ*S/SMSC)=exp2f(c2*S). Validated absmax 0.125.
//
// T=1024 -> NC=16 chunks of CH=64. Chunk c>... warm-up W=320 steps with two
// bracket trajectories (lo from 0, hi from SMSC; monotone map => invariant).
// NEW in R9: hi(+gw) and lo chains run in SEPARATE waves of a 128-thread
// block (2048 waves total = 2/SIMD) and meet through LDS at the chunk start;
// identical ops as R8's fused dstep, but co-resident waves fill each other's
// stall cycles. Merge if gap <= 0.75 (midpoint adopt); unmerged chunks are
// recomputed EXACTLY by pass 2 from the predecessor's end state.
//
// Q[b,t] (t>=1) = fluxes from carry entering step t; Q[b,0] uses the FINAL
// carry (jnp.roll wraparound) with t=0 inputs (chunk NC-1 / pass2 owns it).

struct P {
    float INSC, COEFF, SMSC, RecK, k1, k2, k3, c2;
};

__device__ __forceinline__ P make_params(const float* pINSC, const float* pCOEFF,
                                         const float* pSQ,   const float* pSMSC,
                                         const float* pSUB,  const float* pCRAK,
                                         const float* pRecK) {
    P p;
    p.INSC  = fminf(fmaxf(pINSC[0]  * 5.0f,   0.5f),   5.0f);
    p.COEFF = fminf(fmaxf(pCOEFF[0] * 400.0f, 50.0f),  400.0f);
    float SQ = fminf(fmaxf(pSQ[0]   * 6.0f,   0.0f),   6.0f);
    p.SMSC  = fminf(fmaxf(pSMSC[0]  * 500.0f, 50.0f),  500.0f);
    float SUB  = fminf(fmaxf(pSUB[0],  0.0f), 1.0f);
    float CRAK = fminf(fmaxf(pCRAK[0], 0.0f), 1.0f);
    p.RecK  = fminf(fmaxf(pRecK[0]  * 0.3f,   0.003f), 0.3f);
    float inv = 1.0f / p.SMSC;
    p.k1 = SUB * inv;
    p.k2 = CRAK * inv;
    p.k3 = 10.0f * inv;
    p.c2 = (-SQ * inv) * 1.44269504088896340736f;
    return p;
}

__device__ __forceinline__ float step(float Prec, float PET, float& sms, float& gw, const P& p) {
    float INT   = fminf(fminf(p.INSC, PET), Prec);
    float INR   = Prec - INT;
    float POT   = PET - INT;
    float S     = fmaxf(fminf(sms, p.SMSC), 0.0f);
    float cap   = p.COEFF * exp2f(p.c2 * S);
    float RMO   = fminf(INR, cap);
    float IRUN  = INR - RMO;
    float SRUN  = (p.k1 * S) * RMO;
    float t2    = RMO - SRUN;
    float REC   = (p.k2 * S) * t2;
    float SMF   = t2 - REC;
    float ETS   = fminf(POT, p.k3 * S);
    float s2    = S + (SMF - ETS);
    float RECnew = REC + fmaxf(s2 - p.SMSC, 0.0f);
    float BAS   = p.RecK * gw;
    float Q     = (SRUN + IRUN) + BAS;
    sms = s2;
    gw  = gw + (RECnew - BAS);
    return Q;
}

// Warm-up step, full state, no Q (hi chain / exact chain).
__device__ __forceinline__ void stepw(float Prec, float PET, float& sms, float& gw, const P& p) {
    float INT   = fminf(fminf(p.INSC, PET), Prec);
    float INR   = Prec - INT;
    float POT   = PET - INT;
    float S     = fmaxf(fminf(sms, p.SMSC), 0.0f);
    float cap   = p.COEFF * exp2f(p.c2 * S);
    float RMO   = fminf(INR, cap);
    float SRUN  = (p.k1 * S) * RMO;
    float t2    = RMO - SRUN;
    float REC   = (p.k2 * S) * t2;
    float SMF   = t2 - REC;
    float ETS   = fminf(POT, p.k3 * S);
    float s2    = S + (SMF - ETS);
    float RECnew = REC + fmaxf(s2 - p.SMSC, 0.0f);
    float BAS   = p.RecK * gw;
    sms = s2;
    gw  = gw + (RECnew - BAS);
}

// Warm-up step, sms only (lo chain).
__device__ __forceinline__ void stepl(float Prec, float PET, float& sms, const P& p) {
    float INT   = fminf(fminf(p.INSC, PET), Prec);
    float INR   = Prec - INT;
    float POT   = PET - INT;
    float S     = fmaxf(fminf(sms, p.SMSC), 0.0f);
    float cap   = p.COEFF * exp2f(p.c2 * S);
    float RMO   = fminf(INR, cap);
    float SRUN  = (p.k1 * S) * RMO;
    float t2    = RMO - SRUN;
    float REC   = (p.k2 * S) * t2;
    float SMF   = t2 - REC;
    float ETS   = fminf(POT, p.k3 * S);
    sms = S + (SMF - ETS);
}

#define MERGE_TOL 0.75f

template<int T, int NC, int W>
__global__ __launch_bounds__(128, 2)
void hir_pass1(const float* __restrict__ inputs,
               const float* __restrict__ pINSC,  const float* __restrict__ pCOEFF,
               const float* __restrict__ pSQ,    const float* __restrict__ pSMSC,
               const float* __restrict__ pSUB,   const float* __restrict__ pCRAK,
               const float* __restrict__ pRecK,
               float* __restrict__ out, float4* __restrict__ st, int B)
{
    const int lane = threadIdx.x & 63;
    const int wv   = threadIdx.x >> 6;     // 0 = hi(+gw)+main, 1 = lo bracket
    const int nbg  = B >> 6;               // row groups of 64
    const int bg   = blockIdx.x % nbg;
    const int c    = blockIdx.x / nbg;     // chunk id, block-uniform
    const int b    = (bg << 6) | lane;

    P p = make_params(pINSC, pCOEFF, pSQ, pSMSC, pSUB, pCRAK, pRecK);

    const float4* __restrict__ rp = (const float4*)(inputs + (size_t)b * (2 * T));
    float* __restrict__ orow = out + (size_t)b * T;

    constexpr int CH = T / NC;             // 64 steps
    const int i1 = (c * CH) >> 1;
    const int i2 = ((c + 1) * CH) >> 1;
    int i0 = i1 - (W >> 1);
    const bool exact = (i0 <= 0);
    if (i0 < 0) i0 = 0;

    __shared__ float slo_sh[64];

    float shi = exact ? 0.0f : p.SMSC;     // hi chain state (or exact chain)
    float gw  = 0.0f;
    float slo = 0.0f;

    // ---- Warm-up: depth-2 pipeline of 4-float4 batches (8 steps each) ----
    const int nwb = (i1 - i0) >> 2;        // (i1-i0) % 4 == 0 by construction
    if (wv == 0) {
        if (nwb > 0) {
            float4 A[4], Bq[4], C[4];
            #pragma unroll
            for (int j = 0; j < 4; ++j) A[j] = rp[i0 + j];
            {
                int k1b = (1 < nwb) ? 1 : 0;
                #pragma unroll
                for (int j = 0; j < 4; ++j) Bq[j] = rp[i0 + 4 * k1b + j];
            }
            for (int k = 0; k < nwb; ++k) {
                int kn = (k + 2 < nwb) ? (k + 2) : (nwb - 1);
                #pragma unroll
                for (int j = 0; j < 4; ++j) C[j] = rp[i0 + 4 * kn + j];
                #pragma unroll
                for (int j = 0; j < 4; ++j) {
                    stepw(A[j].x, A[j].y, shi, gw, p);
                    stepw(A[j].z, A[j].w, shi, gw, p);
                }
                #pragma unroll
                for (int j = 0; j < 4; ++j) { A[j] = Bq[j]; Bq[j] = C[j]; }
            }
        }
    } else {
        if (!exact && nwb > 0) {
            float4 A[4], Bq[4], C[4];
            #pragma unroll
            for (int j = 0; j < 4; ++j) A[j] = rp[i0 + j];
            {
                int k1b = (1 < nwb) ? 1 : 0;
                #pragma unroll
                for (int j = 0; j < 4; ++j) Bq[j] = rp[i0 + 4 * k1b + j];
            }
            for (int k = 0; k < nwb; ++k) {
                int kn = (k + 2 < nwb) ? (k + 2) : (nwb - 1);
                #pragma unroll
                for (int j = 0; j < 4; ++j) C[j] = rp[i0 + 4 * kn + j];
                #pragma unroll
                for (int j = 0; j < 4; ++j) {
                    stepl(A[j].x, A[j].y, slo, p);
                    stepl(A[j].z, A[j].w, slo, p);
                }
                #pragma unroll
                for (int j = 0; j < 4; ++j) { A[j] = Bq[j]; Bq[j] = C[j]; }
            }
        }
        slo_sh[lane] = slo;
    }
    __syncthreads();
    if (wv == 1) return;                   // lo wave retires

    float slo_r = slo_sh[lane];
    const bool merged = exact || ((shi - slo_r) <= MERGE_TOL);
    float sms = exact ? shi : (0.5f * (slo_r + shi));

    // ---- Main chunk: 32 float4s, depth-2 pipeline, store Q pairs ----
    {
        constexpr int nmb = (CH / 2) / 4;  // 8 batches
        float4 A[4], Bq[4], C[4];
        #pragma unroll
        for (int j = 0; j < 4; ++j) A[j] = rp[i1 + j];
        #pragma unroll
        for (int j = 0; j < 4; ++j) Bq[j] = rp[i1 + 4 + j];
        for (int k = 0; k < nmb; ++k) {
            int kn = (k + 2 < nmb) ? (k + 2) : (nmb - 1);
            #pragma unroll
            for (int j = 0; j < 4; ++j) C[j] = rp[i1 + 4 * kn + j];
            int ibase = i1 + 4 * k;
            #pragma unroll
            for (int j = 0; j < 4; ++j) {
                float qa = step(A[j].x, A[j].y, sms, gw, p);
                float qb = step(A[j].z, A[j].w, sms, gw, p);
                if (c == 0 && k == 0 && j == 0) {
                    orow[1] = qb;          // t=0 owned by the c=NC-1 path
                } else {
                    ((float2*)orow)[ibase + j] = make_float2(qa, qb);
                }
            }
            #pragma unroll
            for (int j = 0; j < 4; ++j) { A[j] = Bq[j]; Bq[j] = C[j]; }
        }
    }

    st[(size_t)c * B + b] = make_float4(sms, gw, merged ? 1.0f : 0.0f, 0.0f);

    if (c == NC - 1) {
        float4 f0 = rp[0];
        float ss = sms, gg = gw;
        orow[0] = step(f0.x, f0.y, ss, gg, p);
    }
}

template<int T, int NC>
__global__ __launch_bounds__(64, 1)
void hir_pass2(const float* __restrict__ inputs,
               const float* __restrict__ pINSC,  const float* __restrict__ pCOEFF,
               const float* __restrict__ pSQ,    const float* __restrict__ pSMSC,
               const float* __restrict__ pSUB,   const float* __restrict__ pCRAK,
               const float* __restrict__ pRecK,
               float* __restrict__ out, const float4* __restrict__ st, int B)
{
    int b = blockIdx.x * blockDim.x + threadIdx.x;
    if (b >= B) return;

    P p = make_params(pINSC, pCOEFF, pSQ, pSMSC, pSUB, pCRAK, pRecK);
    constexpr int CH = T / NC;

    const float4* __restrict__ rp = (const float4*)(inputs + (size_t)b * (2 * T));
    float* __restrict__ orow = out + (size_t)b * T;

    float4 s0 = st[b];                 // chunk 0: always exact
    float ex_s = s0.x, ex_g = s0.y;

    for (int c = 1; c < NC; ++c) {
        float4 sc = st[(size_t)c * B + b];
        if (sc.z != 0.0f) {
            ex_s = sc.x; ex_g = sc.y;
            continue;
        }
        float sms = ex_s, gw = ex_g;
        const int i1 = (c * CH) >> 1;
        const int i2 = ((c + 1) * CH) >> 1;
        float4 cur = rp[i1];
        for (int i = i1; i < i2; ++i) {
            int ni = (i + 1 < i2) ? (i + 1) : i;
            float4 nxt = rp[ni];
            float qa = step(cur.x, cur.y, sms, gw, p);
            float qb = step(cur.z, cur.w, sms, gw, p);
            ((float2*)orow)[i] = make_float2(qa, qb);
            cur = nxt;
        }
        ex_s = sms; ex_g = gw;
        if (c == NC - 1) {
            float4 f0 = rp[0];
            float ss = sms, gg = gw;
            orow[0] = step(f0.x, f0.y, ss, gg, p);
        }
    }
}

// Fallback: monolithic sequential (odd shapes / tiny workspace).
template<int T>
__global__ __launch_bounds__(64, 1)
void hir_scan_kernel(const float* __restrict__ inputs,
                     const float* __restrict__ pINSC,  const float* __restrict__ pCOEFF,
                     const float* __restrict__ pSQ,    const float* __restrict__ pSMSC,
                     const float* __restrict__ pSUB,   const float* __restrict__ pCRAK,
                     const float* __restrict__ pRecK,
                     float* __restrict__ out, int B)
{
    int b = blockIdx.x * blockDim.x + threadIdx.x;
    if (b >= B) return;
    P p = make_params(pINSC, pCOEFF, pSQ, pSMSC, pSUB, pCRAK, pRecK);
    const float4* __restrict__ rp = (const float4*)(inputs + (size_t)b * (2 * T));
    float* __restrict__ orow = out + (size_t)b * T;
    float sms = 0.0f, gw = 0.0f;
    float4 cur = rp[0];
    const float P0 = cur.x, E0 = cur.y;
    constexpr int NI = T / 2;
    for (int i = 0; i < NI; ++i) {
        int ni = (i + 1 < NI) ? (i + 1) : i;
        float4 nxt = rp[ni];
        float qa = step(cur.x, cur.y, sms, gw, p);
        float qb = step(cur.z, cur.w, sms, gw, p);
        if (i == 0) { orow[1] = qb; }
        else        { ((float2*)orow)[i] = make_float2(qa, qb); }
        cur = nxt;
    }
    float ss = sms, gg = gw;
    orow[0] = step(P0, E0, ss, gg, p);
}

extern "C" void kernel_launch(void* const* d_in, const int* in_sizes, int n_in,
                              void* d_out, int out_size, void* d_ws, size_t ws_size,
                              hipStream_t stream) {
    (void)n_in; (void)out_size;
    constexpr int T  = 1024;
    constexpr int NC = 16;    // chunks (CH=64)
    constexpr int W  = 320;   // warm-up steps (validated: absmax 0.125)
    const float* inputs = (const float*)d_in[0];
    const float* INSC   = (const float*)d_in[1];
    const float* COEFF  = (const float*)d_in[2];
    const float* SQ     = (const float*)d_in[3];
    const float* SMSC   = (const float*)d_in[4];
    const float* SUB    = (const float*)d_in[5];
    const float* CRAK   = (const float*)d_in[6];
    const float* RecK   = (const float*)d_in[7];
    float* out = (float*)d_out;

    int B = in_sizes[0] / (2 * T);            // 4096 for the reference shape
    size_t need = (size_t)B * NC * sizeof(float4);

    if (ws_size < need || (B % 64) != 0) {
        int blocks = (B + 63) / 64;
        hir_scan_kernel<T><<<dim3(blocks), dim3(64), 0, stream>>>(
            inputs, INSC, COEFF, SQ, SMSC, SUB, CRAK, RecK, out, B);
        return;
    }

    float4* st = (float4*)d_ws;
    int nbg = B >> 6;                         // 64 row-groups
    int blocks1 = nbg * NC;                   // 1024 blocks x 128 thr = 2048 waves
    hir_pass1<T, NC, W><<<dim3(blocks1), dim3(128), 0, stream>>>(
        inputs, INSC, COEFF, SQ, SMSC, SUB, CRAK, RecK, out, st, B);
    int blocks2 = (B + 63) / 64;
    hir_pass2<T, NC><<<dim3(blocks2), dim3(64), 0, stream>>>(
        inputs, INSC, COEFF, SQ, SMSC, SUB, CRAK, RecK, out, st, B);
}

// Round 10
// 140.454 us; speedup vs baseline: 1.2799x; 1.2799x over previous
//
#include <hip/hip_runtime.h>
#include <hip/hip_bf16.h>
#include <math.h>

// HIR rainfall-runoff scan — bracketed time-chunking + exact fixup.
// R10: real software pipeline. R8's rotating-copy (A=Bq;Bq=C) forced
// s_waitcnt vmcnt(0) every batch (copies depend on the just-issued loads)
// => prefetch distance was 0 and full memory latency (~250 cyc/step) was
// exposed. Now: 4-slot buffer, phase-constant indexing, load batch k+3
// while consuming batch k — no copies, compiler can hold ~12 loads in
// flight with partial vmcnt waits.
//
// Step math (validated absmax 0.125): heaviside -> min/max (exact,
// continuous at switch points), provably-redundant clamps removed,
// exp(-SQ*S/SMSC)=exp2f(c2*S).
//
// T=1024 -> NC=16 chunks of CH=64. Warm-up W=320 steps with two bracket
// trajectories (lo from 0, hi from SMSC; monotone map => invariant).
// Merge if gap <= 0.75, adopt midpoint; unmerged chunks recomputed EXACTLY
// by pass 2 from predecessor end state. Exact-init chunks run the same
// dual code (both chains bitwise-identical; midpoint 0.5*(x+x)==x).
//
// Q[b,t] (t>=1) = fluxes from carry entering step t; Q[b,0] uses the FINAL
// carry (jnp.roll wraparound) with t=0 inputs (chunk NC-1 / pass2 owns it).

struct P {
    float INSC, COEFF, SMSC, RecK, k1, k2, k3, c2;
};

__device__ __forceinline__ P make_params(const float* pINSC, const float* pCOEFF,
                                         const float* pSQ,   const float* pSMSC,
                                         const float* pSUB,  const float* pCRAK,
                                         const float* pRecK) {
    P p;
    p.INSC  = fminf(fmaxf(pINSC[0]  * 5.0f,   0.5f),   5.0f);
    p.COEFF = fminf(fmaxf(pCOEFF[0] * 400.0f, 50.0f),  400.0f);
    float SQ = fminf(fmaxf(pSQ[0]   * 6.0f,   0.0f),   6.0f);
    p.SMSC  = fminf(fmaxf(pSMSC[0]  * 500.0f, 50.0f),  500.0f);
    float SUB  = fminf(fmaxf(pSUB[0],  0.0f), 1.0f);
    float CRAK = fminf(fmaxf(pCRAK[0], 0.0f), 1.0f);
    p.RecK  = fminf(fmaxf(pRecK[0]  * 0.3f,   0.003f), 0.3f);
    float inv = 1.0f / p.SMSC;
    p.k1 = SUB * inv;
    p.k2 = CRAK * inv;
    p.k3 = 10.0f * inv;
    p.c2 = (-SQ * inv) * 1.44269504088896340736f;
    return p;
}

__device__ __forceinline__ float step(float Prec, float PET, float& sms, float& gw, const P& p) {
    float INT   = fminf(fminf(p.INSC, PET), Prec);
    float INR   = Prec - INT;
    float POT   = PET - INT;
    float S     = fmaxf(fminf(sms, p.SMSC), 0.0f);
    float cap   = p.COEFF * exp2f(p.c2 * S);
    float RMO   = fminf(INR, cap);
    float IRUN  = INR - RMO;
    float SRUN  = (p.k1 * S) * RMO;
    float t2    = RMO - SRUN;
    float REC   = (p.k2 * S) * t2;
    float SMF   = t2 - REC;
    float ETS   = fminf(POT, p.k3 * S);
    float s2    = S + (SMF - ETS);
    float RECnew = REC + fmaxf(s2 - p.SMSC, 0.0f);
    float BAS   = p.RecK * gw;
    float Q     = (SRUN + IRUN) + BAS;
    sms = s2;
    gw  = gw + (RECnew - BAS);
    return Q;
}

// Dual-bracket warm-up step: hi chain carries gw; lo chain is sms-only.
__device__ __forceinline__ void dstep(float Prec, float PET,
                                      float& slo, float& shi, float& gw, const P& p) {
    float INT = fminf(fminf(p.INSC, PET), Prec);
    float INR = Prec - INT;
    float POT = PET - INT;
    {   // hi + gw
        float S     = fmaxf(fminf(shi, p.SMSC), 0.0f);
        float cap   = p.COEFF * exp2f(p.c2 * S);
        float RMO   = fminf(INR, cap);
        float SRUN  = (p.k1 * S) * RMO;
        float t2    = RMO - SRUN;
        float REC   = (p.k2 * S) * t2;
        float SMF   = t2 - REC;
        float ETS   = fminf(POT, p.k3 * S);
        float s2    = S + (SMF - ETS);
        float RECnew = REC + fmaxf(s2 - p.SMSC, 0.0f);
        float BAS   = p.RecK * gw;
        gw  = gw + (RECnew - BAS);
        shi = s2;
    }
    {   // lo, sms only
        float S     = fmaxf(fminf(slo, p.SMSC), 0.0f);
        float cap   = p.COEFF * exp2f(p.c2 * S);
        float RMO   = fminf(INR, cap);
        float SRUN  = (p.k1 * S) * RMO;
        float t2    = RMO - SRUN;
        float REC   = (p.k2 * S) * t2;
        float SMF   = t2 - REC;
        float ETS   = fminf(POT, p.k3 * S);
        slo = S + (SMF - ETS);
    }
}

#define MERGE_TOL 0.75f

template<int T, int NC, int W>
__global__ __launch_bounds__(64, 1)
void hir_pass1(const float* __restrict__ inputs,
               const float* __restrict__ pINSC,  const float* __restrict__ pCOEFF,
               const float* __restrict__ pSQ,    const float* __restrict__ pSMSC,
               const float* __restrict__ pSUB,   const float* __restrict__ pCRAK,
               const float* __restrict__ pRecK,
               float* __restrict__ out, float4* __restrict__ st, int B)
{
    int gid = blockIdx.x * blockDim.x + threadIdx.x;
    int b = gid % B;            // consecutive lanes -> consecutive rows
    int c = gid / B;            // wave-uniform (B % 64 == 0)
    if (c >= NC) return;

    P p = make_params(pINSC, pCOEFF, pSQ, pSMSC, pSUB, pCRAK, pRecK);

    const float4* __restrict__ rp = (const float4*)(inputs + (size_t)b * (2 * T));
    float* __restrict__ orow = out + (size_t)b * T;

    constexpr int CH = T / NC;             // 64 steps
    const int i1 = (c * CH) >> 1;          // first main float4 index
    int i0 = i1 - (W >> 1);                // warm-up start
    const bool exact = (i0 <= 0);
    if (i0 < 0) i0 = 0;

    float slo = 0.0f, shi = exact ? 0.0f : p.SMSC, gw = 0.0f;

    float4 buf[4][4];                      // [phase][j], modulo-scheduled

    // ---- Warm-up: batches of 4 float4 (8 steps), loads issued 3 batches
    //      ahead into a rotating 4-slot buffer (no register copies) ----
    const int nwb = (i1 - i0) >> 2;        // warm-up batches, multiple of 4
    if (nwb > 0) {
        #pragma unroll
        for (int pb = 0; pb < 3; ++pb) {
            int kk = (pb < nwb) ? pb : (nwb - 1);
            #pragma unroll
            for (int j = 0; j < 4; ++j) buf[pb][j] = rp[i0 + 4 * kk + j];
        }
        for (int g = 0; g < (nwb >> 2); ++g) {
            #pragma unroll
            for (int ph = 0; ph < 4; ++ph) {
                int kcur = (g << 2) + ph;
                int kld  = kcur + 3; if (kld > nwb - 1) kld = nwb - 1;
                const int slot = (ph + 3) & 3;    // compile-time constant
                #pragma unroll
                for (int j = 0; j < 4; ++j) buf[slot][j] = rp[i0 + 4 * kld + j];
                #pragma unroll
                for (int j = 0; j < 4; ++j) {
                    dstep(buf[ph][j].x, buf[ph][j].y, slo, shi, gw, p);
                    dstep(buf[ph][j].z, buf[ph][j].w, slo, shi, gw, p);
                }
            }
        }
    }
    const bool merged = exact || ((shi - slo) <= MERGE_TOL);
    float sms = 0.5f * (slo + shi);        // exact: slo==shi bitwise -> == shi

    // ---- Main chunk: 32 float4s, same pipeline, store Q pairs ----
    {
        constexpr int nmb = (CH / 2) / 4;  // 8 batches
        #pragma unroll
        for (int pb = 0; pb < 3; ++pb) {
            #pragma unroll
            for (int j = 0; j < 4; ++j) buf[pb][j] = rp[i1 + 4 * pb + j];
        }
        for (int g = 0; g < (nmb >> 2); ++g) {
            #pragma unroll
            for (int ph = 0; ph < 4; ++ph) {
                int kcur = (g << 2) + ph;
                int kld  = kcur + 3; if (kld > nmb - 1) kld = nmb - 1;
                const int slot = (ph + 3) & 3;
                #pragma unroll
                for (int j = 0; j < 4; ++j) buf[slot][j] = rp[i1 + 4 * kld + j];
                int ibase = i1 + 4 * kcur;
                #pragma unroll
                for (int j = 0; j < 4; ++j) {
                    float qa = step(buf[ph][j].x, buf[ph][j].y, sms, gw, p);
                    float qb = step(buf[ph][j].z, buf[ph][j].w, sms, gw, p);
                    if (c == 0 && kcur == 0 && j == 0) {
                        orow[1] = qb;      // t=0 owned by the c=NC-1 path
                    } else {
                        ((float2*)orow)[ibase + j] = make_float2(qa, qb);
                    }
                }
            }
        }
    }

    st[(size_t)c * B + b] = make_float4(sms, gw, merged ? 1.0f : 0.0f, 0.0f);

    if (c == NC - 1) {
        float4 f0 = rp[0];
        float ss = sms, gg = gw;
        orow[0] = step(f0.x, f0.y, ss, gg, p);
    }
}

template<int T, int NC>
__global__ __launch_bounds__(64, 1)
void hir_pass2(const float* __restrict__ inputs,
               const float* __restrict__ pINSC,  const float* __restrict__ pCOEFF,
               const float* __restrict__ pSQ,    const float* __restrict__ pSMSC,
               const float* __restrict__ pSUB,   const float* __restrict__ pCRAK,
               const float* __restrict__ pRecK,
               float* __restrict__ out, const float4* __restrict__ st, int B)
{
    int b = blockIdx.x * blockDim.x + threadIdx.x;
    if (b >= B) return;

    P p = make_params(pINSC, pCOEFF, pSQ, pSMSC, pSUB, pCRAK, pRecK);
    constexpr int CH = T / NC;

    const float4* __restrict__ rp = (const float4*)(inputs + (size_t)b * (2 * T));
    float* __restrict__ orow = out + (size_t)b * T;

    float4 s0 = st[b];                 // chunk 0: always exact
    float ex_s = s0.x, ex_g = s0.y;

    for (int c = 1; c < NC; ++c) {
        float4 sc = st[(size_t)c * B + b];
        if (sc.z != 0.0f) {
            ex_s = sc.x; ex_g = sc.y;
            continue;
        }
        float sms = ex_s, gw = ex_g;
        const int i1 = (c * CH) >> 1;
        const int i2 = ((c + 1) * CH) >> 1;
        float4 cur = rp[i1];
        for (int i = i1; i < i2; ++i) {
            int ni = (i + 1 < i2) ? (i + 1) : i;
            float4 nxt = rp[ni];
            float qa = step(cur.x, cur.y, sms, gw, p);
            float qb = step(cur.z, cur.w, sms, gw, p);
            ((float2*)orow)[i] = make_float2(qa, qb);
            cur = nxt;
        }
        ex_s = sms; ex_g = gw;
        if (c == NC - 1) {
            float4 f0 = rp[0];
            float ss = sms, gg = gw;
            orow[0] = step(f0.x, f0.y, ss, gg, p);
        }
    }
}

// Fallback: monolithic sequential (odd shapes / tiny workspace).
template<int T>
__global__ __launch_bounds__(64, 1)
void hir_scan_kernel(const float* __restrict__ inputs,
                     const float* __restrict__ pINSC,  const float* __restrict__ pCOEFF,
                     const float* __restrict__ pSQ,    const float* __restrict__ pSMSC,
                     const float* __restrict__ pSUB,   const float* __restrict__ pCRAK,
                     const float* __restrict__ pRecK,
                     float* __restrict__ out, int B)
{
    int b = blockIdx.x * blockDim.x + threadIdx.x;
    if (b >= B) return;
    P p = make_params(pINSC, pCOEFF, pSQ, pSMSC, pSUB, pCRAK, pRecK);
    const float4* __restrict__ rp = (const float4*)(inputs + (size_t)b * (2 * T));
    float* __restrict__ orow = out + (size_t)b * T;
    float sms = 0.0f, gw = 0.0f;
    float4 cur = rp[0];
    const float P0 = cur.x, E0 = cur.y;
    constexpr int NI = T / 2;
    for (int i = 0; i < NI; ++i) {
        int ni = (i + 1 < NI) ? (i + 1) : i;
        float4 nxt = rp[ni];
        float qa = step(cur.x, cur.y, sms, gw, p);
        float qb = step(cur.z, cur.w, sms, gw, p);
        if (i == 0) { orow[1] = qb; }
        else        { ((float2*)orow)[i] = make_float2(qa, qb); }
        cur = nxt;
    }
    float ss = sms, gg = gw;
    orow[0] = step(P0, E0, ss, gg, p);
}

extern "C" void kernel_launch(void* const* d_in, const int* in_sizes, int n_in,
                              void* d_out, int out_size, void* d_ws, size_t ws_size,
                              hipStream_t stream) {
    (void)n_in; (void)out_size;
    constexpr int T  = 1024;
    constexpr int NC = 16;    // chunks (CH=64)
    constexpr int W  = 320;   // warm-up steps (validated: absmax 0.125)
    const float* inputs = (const float*)d_in[0];
    const float* INSC   = (const float*)d_in[1];
    const float* COEFF  = (const float*)d_in[2];
    const float* SQ     = (const float*)d_in[3];
    const float* SMSC   = (const float*)d_in[4];
    const float* SUB    = (const float*)d_in[5];
    const float* CRAK   = (const float*)d_in[6];
    const float* RecK   = (const float*)d_in[7];
    float* out = (float*)d_out;

    int B = in_sizes[0] / (2 * T);            // 4096 for the reference shape
    size_t need = (size_t)B * NC * sizeof(float4);

    if (ws_size < need || (B % 64) != 0) {
        int blocks = (B + 63) / 64;
        hir_scan_kernel<T><<<dim3(blocks), dim3(64), 0, stream>>>(
            inputs, INSC, COEFF, SQ, SMSC, SUB, CRAK, RecK, out, B);
        return;
    }

    float4* st = (float4*)d_ws;
    long total = (long)B * NC;                // 65536 threads = 1024 waves
    int blocks1 = (int)((total + 63) / 64);
    hir_pass1<T, NC, W><<<dim3(blocks1), dim3(64), 0, stream>>>(
        inputs, INSC, COEFF, SQ, SMSC, SUB, CRAK, RecK, out, st, B);
    int blocks2 = (B + 63) / 64;
    hir_pass2<T, NC><<<dim3(blocks2), dim3(64), 0, stream>>>(
        inputs, INSC, COEFF, SQ, SMSC, SUB, CRAK, RecK, out, st, B);
}